// Round 4
// baseline (1059.878 us; speedup 1.0000x reference)
//
#include <hip/hip_runtime.h>

#define FIN 100
#define FHID 100
#define FEMB 64
#define NCLS 40
#define H1STR 112             // padded row stride for h1: 14 x ushort8, 224B rows (pad cols 100..111 zeroed)

#define SBSH 8                // 256 nodes per super-bucket
#define CAPB 24               // LDS bin capacity per block
#define SBCAP 4608            // per-super-bucket arena cap: mean 4096 + 8 sigma
#define CSTR 16               // cursor stride in ints
#define EPB 2048              // edges per scatter block

typedef __attribute__((ext_vector_type(8))) short short8;          // MFMA A/B frag
typedef __attribute__((ext_vector_type(8))) unsigned short u16x8;  // 16B bf16 gather
typedef __attribute__((ext_vector_type(4))) float f32x4;           // MFMA C/D frag

// ---------- bf16 helpers (RNE) ----------
__device__ inline unsigned short f2bf(float f) {
    unsigned u = __float_as_uint(f);
    u += 0x7FFFu + ((u >> 16) & 1u);
    return (unsigned short)(u >> 16);
}
__device__ inline float bf2f(unsigned short s) {
    return __uint_as_float((unsigned)s << 16);
}

// ====== 4-wave MFMA tiles (for GEMM1 inside k_front; 256-thread blocks, multi-pass) ======
template <int KP, int KOUT, int NTY, bool BIAS, bool OUT_BF16, int OSTR>
__device__ __forceinline__ void mfma_tiles4(const unsigned short* Abf, const unsigned short* Wt,
                                            const float* __restrict__ bias, void* __restrict__ C,
                                            int n, int row0, int tb) {
    constexpr int APAD  = KP + 8;
    constexpr int NKC   = KP / 32;
    constexpr int TQ    = (NTY + 1) / 2;
    constexpr int NTALL = (KOUT + 15) / 16;

    const int tid  = threadIdx.x;
    const int lane = tid & 63;
    const int w    = tid >> 6;
    const int m0   = (w >> 1) * 64;
    const int t0   = (w & 1) * TQ;
    const int lm   = lane & 15;
    const int quad = lane >> 4;

    const int ntloc = (NTALL - tb < NTY) ? (NTALL - tb) : NTY;
    const int tcnt  = (ntloc - t0 < TQ) ? (ntloc - t0) : TQ;

    f32x4 acc[4][TQ];
    #pragma unroll
    for (int i = 0; i < 4; ++i)
        #pragma unroll
        for (int t = 0; t < TQ; ++t)
            acc[i][t] = (f32x4)(0.f);

    for (int kt = 0; kt < NKC; ++kt) {
        short8 a[4], b[TQ];
        #pragma unroll
        for (int i = 0; i < 4; ++i)
            a[i] = *(const short8*)&Abf[(m0 + i * 16 + lm) * APAD + kt * 32 + quad * 8];
        #pragma unroll
        for (int t = 0; t < TQ; ++t)
            if (t < tcnt)
                b[t] = *(const short8*)&Wt[((t0 + t) * 16 + lm) * APAD + kt * 32 + quad * 8];
        #pragma unroll
        for (int i = 0; i < 4; ++i)
            #pragma unroll
            for (int t = 0; t < TQ; ++t)
                if (t < tcnt)
                    acc[i][t] = __builtin_amdgcn_mfma_f32_16x16x32_bf16(a[i], b[t], acc[i][t], 0, 0, 0);
    }

    #pragma unroll
    for (int t = 0; t < TQ; ++t) {
        if (t >= tcnt) continue;
        int col = (tb + t0 + t) * 16 + lm;
        if (col >= KOUT) continue;
        float bv = 0.f;
        if constexpr (BIAS) bv = bias[col];
        #pragma unroll
        for (int i = 0; i < 4; ++i) {
            #pragma unroll
            for (int rg = 0; rg < 4; ++rg) {
                int row = row0 + m0 + i * 16 + quad * 4 + rg;
                if (row < n) {
                    float v = acc[i][t][rg] + bv;
                    if constexpr (OUT_BF16)
                        ((unsigned short*)C)[(size_t)row * OSTR + col] = f2bf(v);
                    else
                        ((float*)C)[(size_t)row * OSTR + col] = v;
                }
            }
        }
    }
}

// ====== GEMM1 body: stage fp32 A -> bf16 LDS, multi-pass Wt, 256 threads ======
template <int KIN, int KOUT, int NTY, bool OUT_BF16, int ASTR, int OSTR>
__device__ __forceinline__ void gemm_body(const void* __restrict__ A, const float* __restrict__ W,
                                          void* __restrict__ C, int n, int bid, char* smem) {
    constexpr int KP    = ((KIN + 31) / 32) * 32;
    constexpr int NTALL = (KOUT + 15) / 16;
    constexpr int NTC   = NTY * 16;
    constexpr int APAD  = KP + 8;
    constexpr int KQ4   = KIN / 4;

    unsigned short* Abf = (unsigned short*)smem;               // 128 * APAD
    unsigned short* Wt  = Abf + 128 * APAD;                    // NTC * APAD

    const int row0 = bid * 128;
    const int tid  = threadIdx.x;

    {   // stage A (fp32 -> bf16)
        const float* Af = (const float*)A;
        for (int idx = tid; idx < 128 * KQ4; idx += 256) {
            int r = idx / KQ4;
            int kq = idx - r * KQ4;
            float4 v = make_float4(0.f, 0.f, 0.f, 0.f);
            if (row0 + r < n) v = ((const float4*)(Af + (size_t)(row0 + r) * ASTR))[kq];
            ushort4 o;
            o.x = f2bf(v.x); o.y = f2bf(v.y); o.z = f2bf(v.z); o.w = f2bf(v.w);
            *(ushort4*)&Abf[r * APAD + kq * 4] = o;
        }
    }
    if constexpr (KP > KIN) {
        constexpr int PADW = KP - KIN;
        for (int idx = tid; idx < 128 * PADW; idx += 256) {
            int r = idx / PADW;
            Abf[r * APAD + KIN + (idx - r * PADW)] = 0;
        }
    }
    // zero output pad columns (downstream u16x8 gathers read exact zeros)
    if constexpr (OUT_BF16 && (OSTR > KOUT)) {
        constexpr int PW = OSTR - KOUT;
        for (int idx = tid; idx < 128 * PW; idx += 256) {
            int r = idx / PW;
            int c = idx - r * PW;
            if (row0 + r < n)
                ((unsigned short*)C)[(size_t)(row0 + r) * OSTR + KOUT + c] = 0;
        }
    }

    for (int tb = 0; tb < NTALL; tb += NTY) {
        for (int idx = tid; idx < KIN * NTC; idx += 256) {
            int k = idx / NTC;
            int c = idx - k * NTC;
            int gc = tb * 16 + c;
            float v = (gc < KOUT) ? W[(size_t)k * KOUT + gc] : 0.f;
            Wt[c * APAD + k] = f2bf(v);
        }
        if constexpr (KP > KIN) {
            constexpr int PADW = KP - KIN;
            for (int idx = tid; idx < NTC * PADW; idx += 256) {
                int c = idx / PADW;
                Wt[c * APAD + KIN + (idx - c * PADW)] = 0;
            }
        }
        __syncthreads();
        mfma_tiles4<KP, KOUT, NTY, false, OUT_BF16, OSTR>(Abf, Wt, nullptr, C, n, row0, tb);
        __syncthreads();
    }
}

// ====== merged front: edge scatter + deg histogram (blocks [0,scb)) || GEMM1 (blocks [scb,scb+nmb)) ======
#define SMEM_FRONT ((128 + 64) * (128 + 8) * 2)   // 52224B; gemm1 is the larger user
__global__ __launch_bounds__(256) void k_front(const int* __restrict__ src,
                                               const int* __restrict__ dst,
                                               int* __restrict__ gcur,
                                               int* __restrict__ arena,
                                               int* __restrict__ deg,
                                               int E, int nsb, int scb,
                                               const float* __restrict__ x,
                                               const float* __restrict__ W1,
                                               unsigned short* __restrict__ h1, int n) {
    __shared__ __attribute__((aligned(16))) char smem[SMEM_FRONT];
    static_assert(SMEM_FRONT >= (int)(256 * CAPB * 4 + 2 * 256 * 4), "scatter fits");
    if ((int)blockIdx.x < scb) {
        int* bins  = (int*)smem;            // 256*CAPB
        int* bcnt  = bins + 256 * CAPB;     // 256
        int* pbase = bcnt + 256;            // 256
        const int tid = threadIdx.x;
        bcnt[tid] = 0;
        __syncthreads();

        const int e0 = blockIdx.x * EPB;
        for (int k = 0; k < EPB / 256; ++k) {
            int e = e0 + k * 256 + tid;
            if (e < E) {
                int d = dst[e];
                atomicAdd(&deg[d], 1);                     // degree histogram (replaces the sort kernel)
                int sb = d >> SBSH;
                int rec = (src[e] << SBSH) | (d & 255);
                int c = atomicAdd(&bcnt[sb], 1);
                if (c < CAPB) {
                    bins[sb * CAPB + c] = rec;
                } else {  // rare overflow: direct global append
                    int p = atomicAdd(&gcur[sb * CSTR], 1);
                    if (p < SBCAP) arena[(size_t)sb * SBCAP + p] = rec;
                }
            }
        }
        __syncthreads();

        if (tid < nsb) {
            int c = bcnt[tid];
            if (c > CAPB) c = CAPB;
            pbase[tid] = (c > 0) ? atomicAdd(&gcur[tid * CSTR], c) : 0;
        }
        __syncthreads();

        const int wv = tid >> 6, lane = tid & 63;
        for (int sb = wv; sb < nsb; sb += 4) {
            int c = bcnt[sb];
            if (c > CAPB) c = CAPB;
            int p = pbase[sb];
            if (lane < c && p + lane < SBCAP)
                arena[(size_t)sb * SBCAP + p + lane] = bins[sb * CAPB + lane];
        }
    } else {
        gemm_body<FIN, FHID, 4, true, FIN, H1STR>(x, W1, h1, n, (int)blockIdx.x - scb, smem);
    }
}

// ====== 16-wave single-pass MFMA tiles (1024-thread fused kernels) ======
template <int KP, int KOUT, int NTY, bool BIAS, bool OUT_BF16, int OSTR>
__device__ __forceinline__ void mfma_tiles16(const unsigned short* Abf, const unsigned short* Wt,
                                             const float* __restrict__ bias, void* __restrict__ C,
                                             int n, int row0) {
    constexpr int APAD  = KP + 8;
    constexpr int NKC   = KP / 32;
    constexpr int TQ    = (NTY + 1) / 2;
    constexpr int NTALL = (KOUT + 15) / 16;

    const int tid  = threadIdx.x;
    const int lane = tid & 63;
    const int w    = tid >> 6;          // 0..15
    const int m0   = (w >> 1) * 16;     // 16-row strip per wave pair
    const int t0   = (w & 1) * TQ;
    const int lm   = lane & 15;
    const int quad = lane >> 4;
    const int tcnt = (NTALL - t0 < TQ) ? (NTALL - t0) : TQ;

    f32x4 acc[TQ];
    #pragma unroll
    for (int t = 0; t < TQ; ++t) acc[t] = (f32x4)(0.f);

    for (int kt = 0; kt < NKC; ++kt) {
        short8 a = *(const short8*)&Abf[(m0 + lm) * APAD + kt * 32 + quad * 8];
        short8 b[TQ];
        #pragma unroll
        for (int t = 0; t < TQ; ++t)
            if (t < tcnt)
                b[t] = *(const short8*)&Wt[((t0 + t) * 16 + lm) * APAD + kt * 32 + quad * 8];
        #pragma unroll
        for (int t = 0; t < TQ; ++t)
            if (t < tcnt)
                acc[t] = __builtin_amdgcn_mfma_f32_16x16x32_bf16(a, b[t], acc[t], 0, 0, 0);
    }

    #pragma unroll
    for (int t = 0; t < TQ; ++t) {
        if (t >= tcnt) continue;
        int col = (t0 + t) * 16 + lm;
        if (col >= KOUT) continue;
        float bv = 0.f;
        if constexpr (BIAS) bv = bias[col];
        #pragma unroll
        for (int rg = 0; rg < 4; ++rg) {
            int row = row0 + m0 + quad * 4 + rg;
            if (row < n) {
                float v = acc[t][rg] + bv;
                if constexpr (OUT_BF16)
                    ((unsigned short*)C)[(size_t)row * OSTR + col] = f2bf(v);
                else
                    ((float*)C)[(size_t)row * OSTR + col] = v;
            }
        }
    }
}

// ====== fused LDS-accumulate aggregation + GEMM ======
// Block b: 128 dst rows (half of super-bucket sb = b>>1).  Phases:
//   (1) zero fp32 LDS acc + stage Wt (single pass);
//   (2) stream arena segment, edge-parallel: LPE lanes per edge each gather one u16x8 of
//       h[src], scale by rsqrt(deg[src]+1), fire-and-forget ds_add_f32 into acc
//       (no carried register dependency -> iterations overlap freely);
//   (3) finalize: relu(dinv_i*(acc + dinv_i*h_self) + agg_bias) -> bf16 straight into Abf;
//   (4) single-pass 16-wave MFMA -> C.
// LPE must be a power of two.
template <int FAGG, int NG, int HSTR, int ACCS, int KIN, int KOUT, int NTY,
          bool GBIAS, bool OUT_BF16, int OSTR, int LPE>
__global__ __launch_bounds__(1024) void k_agg_gemm(const unsigned short* __restrict__ h,
                                                   const int* __restrict__ arena,
                                                   const int* __restrict__ gcur,
                                                   const int* __restrict__ deg,
                                                   const float* __restrict__ ab,
                                                   const float* __restrict__ W,
                                                   const float* __restrict__ gb,
                                                   void* __restrict__ C, int n) {
    constexpr int KP   = ((KIN + 31) / 32) * 32;
    constexpr int APAD = KP + 8;
    constexpr int NTC  = NTY * 16;
    static_assert((LPE & (LPE - 1)) == 0, "LPE pow2");

    __shared__ float sAcc[128 * ACCS];
    __shared__ __attribute__((aligned(16))) unsigned short Abf[128 * APAD];
    __shared__ __attribute__((aligned(16))) unsigned short Wt[NTC * APAD];

    const int tid  = threadIdx.x;
    const int bid  = blockIdx.x;
    const int sb   = bid >> 1;
    const int half = bid & 1;
    const int row0 = bid * 128;

    // ---- (1) zero acc + stage Wt ----
    for (int idx = tid; idx < 128 * ACCS; idx += 1024) sAcc[idx] = 0.f;
    for (int idx = tid; idx < KIN * NTC; idx += 1024) {
        int k = idx / NTC;
        int c = idx - k * NTC;
        float v = (c < KOUT) ? W[(size_t)k * KOUT + c] : 0.f;
        Wt[c * APAD + k] = f2bf(v);
    }
    if constexpr (KP > KIN) {
        constexpr int PADW = KP - KIN;
        for (int idx = tid; idx < NTC * PADW; idx += 1024) {
            int c = idx / PADW;
            Wt[c * APAD + KIN + (idx - c * PADW)] = 0;
        }
    }
    __syncthreads();

    // ---- (2) stream edges ----
    {
        int len = gcur[sb * CSTR];
        if (len > SBCAP) len = SBCAP;
        if (len < 0) len = 0;
        const int* seg = arena + (size_t)sb * SBCAP;
        const int wv   = tid >> 6;
        const int lane = tid & 63;
        const int sub  = lane >> __builtin_ctz(LPE);   // edge slot within wave
        const int g    = lane & (LPE - 1);             // feature group
        constexpr int EPW   = 64 / LPE;                // edges per wave
        constexpr int CHUNK = 16 * EPW;                // edges per block-iteration

        for (int eb = wv * EPW; eb < len; eb += CHUNK) {
            int e = eb + sub;
            if (e < len && g < NG) {
                int rec  = seg[e];
                int dstl = rec & 255;
                if ((dstl >> 7) == half) {
                    int s = rec >> SBSH;
                    float ws = rsqrtf((float)deg[s] + 1.0f);
                    u16x8 u = *(const u16x8*)&h[(size_t)s * HSTR + g * 8];
                    float* ar = &sAcc[(dstl & 127) * ACCS + g * 8];
                    #pragma unroll
                    for (int j = 0; j < 8; ++j)
                        atomicAdd(&ar[j], bf2f(u[j]) * ws);
                }
            }
        }
    }
    __syncthreads();

    // ---- (3) finalize -> Abf (bf16) ----
    for (int idx = tid; idx < 128 * NG; idx += 1024) {
        int r = idx / NG;
        int g = idx - r * NG;
        int i = row0 + r;
        u16x8 o;
        #pragma unroll
        for (int j = 0; j < 8; ++j) o[j] = 0;
        if (i < n) {
            float di = rsqrtf((float)deg[i] + 1.0f);
            u16x8 hs = *(const u16x8*)&h[(size_t)i * HSTR + g * 8];
            #pragma unroll
            for (int j = 0; j < 8; ++j) {
                int col = g * 8 + j;
                float bj = (col < FAGG) ? ab[col] : 0.f;
                float v = fmaf(di, fmaf(di, bf2f(hs[j]), sAcc[r * ACCS + col]), bj);
                o[j] = f2bf(fmaxf(v, 0.f));
            }
        }
        *(u16x8*)&Abf[r * APAD + g * 8] = o;
    }
    if constexpr (KP > NG * 8) {             // zero A pad cols [NG*8, KP)
        constexpr int PW = KP - NG * 8;
        for (int idx = tid; idx < 128 * PW; idx += 1024) {
            int r = idx / PW;
            Abf[r * APAD + NG * 8 + (idx - r * PW)] = 0;
        }
    }
    __syncthreads();

    // ---- (4) GEMM ----
    mfma_tiles16<KP, KOUT, NTY, GBIAS, OUT_BF16, OSTR>(Abf, Wt, gb, C, n, row0);
}

extern "C" void kernel_launch(void* const* d_in, const int* in_sizes, int n_in,
                              void* d_out, int out_size, void* d_ws, size_t ws_size,
                              hipStream_t stream) {
    const float* x  = (const float*)d_in[0];
    const int*   ei = (const int*)d_in[1];
    const float* W1 = (const float*)d_in[2];
    const float* b1 = (const float*)d_in[3];
    const float* W2 = (const float*)d_in[4];
    const float* b2 = (const float*)d_in[5];
    const float* Wc = (const float*)d_in[6];
    const float* bc = (const float*)d_in[7];
    float* out = (float*)d_out;

    const int N = in_sizes[0] / FIN;
    const int E = in_sizes[1] / 2;
    const int* src = ei;
    const int* dst = ei + E;
    const int NSB = (N + 255) >> SBSH;       // 196
    const int SCB = (E + EPB - 1) / EPB;     // 391

    auto align = [](size_t v) { return (v + 255) & ~(size_t)255; };
    char* ws = (char*)d_ws;
    const size_t cur_bytes = align((size_t)256 * CSTR * 4);
    const size_t deg_bytes = align((size_t)N * 4);
    int* gcur = (int*)ws;   ws += cur_bytes;
    int* deg  = (int*)ws;   ws += deg_bytes;         // contiguous with gcur -> one memset
    int* arena = (int*)ws;  ws += align((size_t)NSB * SBCAP * 4);
    unsigned short* h1 = (unsigned short*)ws; ws += align((size_t)N * H1STR * 2);
    unsigned short* h2 = (unsigned short*)ws; ws += align((size_t)N * FEMB * 2);

    const int nmb = (N + 127) / 128;         // 391 GEMM1 row-tiles

    // 1) zero cursors + degree histogram (one node)
    hipMemsetAsync(gcur, 0, cur_bytes + deg_bytes, stream);

    // 2) merged: edge scatter + deg (blocks [0,SCB)) || GEMM1 h1 = x@W1 (blocks [SCB,SCB+nmb))
    k_front<<<SCB + nmb, 256, 0, stream>>>(src, dst, gcur, arena, deg, E, NSB, SCB, x, W1, h1, N);

    // 3) fused layer 2: a1 = relu(agg(h1)+b1) in LDS; h2 = a1 @ W2  (bf16, stride FEMB)
    k_agg_gemm<FHID, 13, H1STR, 108, FHID, FEMB, 4, false, true, FEMB, 16>
        <<<2 * NSB, 1024, 0, stream>>>(h1, arena, gcur, deg, b1, W2, nullptr, h2, N);

    // 4) fused layer 3: a2 = relu(agg(h2)+b2) in LDS; out = a2 @ Wc + bc  (fp32)
    k_agg_gemm<FEMB, 8, FEMB, 68, FEMB, NCLS, 3, true, false, NCLS, 8>
        <<<2 * NSB, 1024, 0, stream>>>(h2, arena, gcur, deg, b2, Wc, bc, out, N);
}

// Round 5
// 182.130 us; speedup vs baseline: 5.8194x; 5.8194x over previous
//
#include <hip/hip_runtime.h>

#define FIN 100
#define FHID 100
#define FEMB 64
#define NCLS 40
#define H1STR 112             // padded row stride for h1: 14 x ushort8, 224B rows (pad cols 100..111 zeroed)

#define SBSH 8                // 256 nodes per super-bucket
#define CAPB 24               // LDS bin capacity per block
#define SBCAP 4608            // per-super-bucket arena cap: mean 4096 + 8 sigma
#define CSTR 16               // cursor stride in ints
#define EPB 2048              // edges per scatter block

typedef __attribute__((ext_vector_type(8))) short short8;          // MFMA A/B frag
typedef __attribute__((ext_vector_type(8))) unsigned short u16x8;  // 16B bf16 gather
typedef __attribute__((ext_vector_type(4))) float f32x4;           // MFMA C/D frag

// ---------- bf16 helpers (RNE) ----------
__device__ inline unsigned short f2bf(float f) {
    unsigned u = __float_as_uint(f);
    u += 0x7FFFu + ((u >> 16) & 1u);
    return (unsigned short)(u >> 16);
}
__device__ inline float bf2f(unsigned short s) {
    return __uint_as_float((unsigned)s << 16);
}

// ====== 4-wave MFMA tiles (GEMM1 inside k_front; 256 threads, multi-pass) ======
template <int KP, int KOUT, int NTY, bool BIAS, bool OUT_BF16, int OSTR>
__device__ __forceinline__ void mfma_tiles4(const unsigned short* Abf, const unsigned short* Wt,
                                            const float* __restrict__ bias, void* __restrict__ C,
                                            int n, int row0, int tb) {
    constexpr int APAD  = KP + 8;
    constexpr int NKC   = KP / 32;
    constexpr int TQ    = (NTY + 1) / 2;
    constexpr int NTALL = (KOUT + 15) / 16;

    const int tid  = threadIdx.x;
    const int lane = tid & 63;
    const int w    = tid >> 6;
    const int m0   = (w >> 1) * 64;
    const int t0   = (w & 1) * TQ;
    const int lm   = lane & 15;
    const int quad = lane >> 4;

    const int ntloc = (NTALL - tb < NTY) ? (NTALL - tb) : NTY;
    const int tcnt  = (ntloc - t0 < TQ) ? (ntloc - t0) : TQ;

    f32x4 acc[4][TQ];
    #pragma unroll
    for (int i = 0; i < 4; ++i)
        #pragma unroll
        for (int t = 0; t < TQ; ++t)
            acc[i][t] = (f32x4)(0.f);

    for (int kt = 0; kt < NKC; ++kt) {
        short8 a[4], b[TQ];
        #pragma unroll
        for (int i = 0; i < 4; ++i)
            a[i] = *(const short8*)&Abf[(m0 + i * 16 + lm) * APAD + kt * 32 + quad * 8];
        #pragma unroll
        for (int t = 0; t < TQ; ++t)
            if (t < tcnt)
                b[t] = *(const short8*)&Wt[((t0 + t) * 16 + lm) * APAD + kt * 32 + quad * 8];
        #pragma unroll
        for (int i = 0; i < 4; ++i)
            #pragma unroll
            for (int t = 0; t < TQ; ++t)
                if (t < tcnt)
                    acc[i][t] = __builtin_amdgcn_mfma_f32_16x16x32_bf16(a[i], b[t], acc[i][t], 0, 0, 0);
    }

    #pragma unroll
    for (int t = 0; t < TQ; ++t) {
        if (t >= tcnt) continue;
        int col = (tb + t0 + t) * 16 + lm;
        if (col >= KOUT) continue;
        float bv = 0.f;
        if constexpr (BIAS) bv = bias[col];
        #pragma unroll
        for (int i = 0; i < 4; ++i) {
            #pragma unroll
            for (int rg = 0; rg < 4; ++rg) {
                int row = row0 + m0 + i * 16 + quad * 4 + rg;
                if (row < n) {
                    float v = acc[i][t][rg] + bv;
                    if constexpr (OUT_BF16)
                        ((unsigned short*)C)[(size_t)row * OSTR + col] = f2bf(v);
                    else
                        ((float*)C)[(size_t)row * OSTR + col] = v;
                }
            }
        }
    }
}

// ====== GEMM1 body: stage fp32 A -> bf16 LDS, multi-pass Wt, 256 threads ======
template <int KIN, int KOUT, int NTY, bool OUT_BF16, int ASTR, int OSTR>
__device__ __forceinline__ void gemm_body(const void* __restrict__ A, const float* __restrict__ W,
                                          void* __restrict__ C, int n, int bid, char* smem) {
    constexpr int KP    = ((KIN + 31) / 32) * 32;
    constexpr int NTALL = (KOUT + 15) / 16;
    constexpr int NTC   = NTY * 16;
    constexpr int APAD  = KP + 8;
    constexpr int KQ4   = KIN / 4;

    unsigned short* Abf = (unsigned short*)smem;               // 128 * APAD
    unsigned short* Wt  = Abf + 128 * APAD;                    // NTC * APAD

    const int row0 = bid * 128;
    const int tid  = threadIdx.x;

    {   // stage A (fp32 -> bf16)
        const float* Af = (const float*)A;
        for (int idx = tid; idx < 128 * KQ4; idx += 256) {
            int r = idx / KQ4;
            int kq = idx - r * KQ4;
            float4 v = make_float4(0.f, 0.f, 0.f, 0.f);
            if (row0 + r < n) v = ((const float4*)(Af + (size_t)(row0 + r) * ASTR))[kq];
            ushort4 o;
            o.x = f2bf(v.x); o.y = f2bf(v.y); o.z = f2bf(v.z); o.w = f2bf(v.w);
            *(ushort4*)&Abf[r * APAD + kq * 4] = o;
        }
    }
    if constexpr (KP > KIN) {
        constexpr int PADW = KP - KIN;
        for (int idx = tid; idx < 128 * PADW; idx += 256) {
            int r = idx / PADW;
            Abf[r * APAD + KIN + (idx - r * PADW)] = 0;
        }
    }
    // zero output pad columns (downstream u16x8 gathers read exact zeros)
    if constexpr (OUT_BF16 && (OSTR > KOUT)) {
        constexpr int PW = OSTR - KOUT;
        for (int idx = tid; idx < 128 * PW; idx += 256) {
            int r = idx / PW;
            int c = idx - r * PW;
            if (row0 + r < n)
                ((unsigned short*)C)[(size_t)(row0 + r) * OSTR + KOUT + c] = 0;
        }
    }

    for (int tb = 0; tb < NTALL; tb += NTY) {
        for (int idx = tid; idx < KIN * NTC; idx += 256) {
            int k = idx / NTC;
            int c = idx - k * NTC;
            int gc = tb * 16 + c;
            float v = (gc < KOUT) ? W[(size_t)k * KOUT + gc] : 0.f;
            Wt[c * APAD + k] = f2bf(v);
        }
        if constexpr (KP > KIN) {
            constexpr int PADW = KP - KIN;
            for (int idx = tid; idx < NTC * PADW; idx += 256) {
                int c = idx / PADW;
                Wt[c * APAD + KIN + (idx - c * PADW)] = 0;
            }
        }
        __syncthreads();
        mfma_tiles4<KP, KOUT, NTY, false, OUT_BF16, OSTR>(Abf, Wt, nullptr, C, n, row0, tb);
        __syncthreads();
    }
}

// ====== merged front: edge scatter-binning (blocks [0,scb)) || GEMM1 (blocks [scb,scb+nmb)) ======
#define SMEM_FRONT ((128 + 64) * (128 + 8) * 2)   // 52224B; gemm1 is the larger user
__global__ __launch_bounds__(256) void k_front(const int* __restrict__ src,
                                               const int* __restrict__ dst,
                                               int* __restrict__ gcur,
                                               int* __restrict__ arena,
                                               int E, int nsb, int scb,
                                               const float* __restrict__ x,
                                               const float* __restrict__ W1,
                                               unsigned short* __restrict__ h1, int n) {
    __shared__ __attribute__((aligned(16))) char smem[SMEM_FRONT];
    static_assert(SMEM_FRONT >= (int)(256 * CAPB * 4 + 2 * 256 * 4), "scatter fits");
    if ((int)blockIdx.x < scb) {
        int* bins  = (int*)smem;            // 256*CAPB
        int* bcnt  = bins + 256 * CAPB;     // 256
        int* pbase = bcnt + 256;            // 256
        const int tid = threadIdx.x;
        bcnt[tid] = 0;
        __syncthreads();

        const int e0 = blockIdx.x * EPB;
        for (int k = 0; k < EPB / 256; ++k) {
            int e = e0 + k * 256 + tid;
            if (e < E) {
                int d = dst[e];
                int sb = d >> SBSH;
                int rec = (src[e] << SBSH) | (d & 255);
                int c = atomicAdd(&bcnt[sb], 1);
                if (c < CAPB) {
                    bins[sb * CAPB + c] = rec;
                } else {  // rare overflow: direct global append
                    int p = atomicAdd(&gcur[sb * CSTR], 1);
                    if (p < SBCAP) arena[(size_t)sb * SBCAP + p] = rec;
                }
            }
        }
        __syncthreads();

        if (tid < nsb) {
            int c = bcnt[tid];
            if (c > CAPB) c = CAPB;
            pbase[tid] = (c > 0) ? atomicAdd(&gcur[tid * CSTR], c) : 0;
        }
        __syncthreads();

        const int wv = tid >> 6, lane = tid & 63;
        for (int sb = wv; sb < nsb; sb += 4) {
            int c = bcnt[sb];
            if (c > CAPB) c = CAPB;
            int p = pbase[sb];
            if (lane < c && p + lane < SBCAP)
                arena[(size_t)sb * SBCAP + p + lane] = bins[sb * CAPB + lane];
        }
    } else {
        gemm_body<FIN, FHID, 4, true, FIN, H1STR>(x, W1, h1, n, (int)blockIdx.x - scb, smem);
    }
}

// ====== per-super-bucket sort: 1024 threads (verified in R1) ======
__global__ __launch_bounds__(1024) void k_bucket_sort(const int* __restrict__ arena,
                                                      const int* __restrict__ gcur,
                                                      int* __restrict__ gcounter,
                                                      int* __restrict__ rowptr,
                                                      int* __restrict__ rowend,
                                                      float* __restrict__ dinv,
                                                      int* __restrict__ src_sorted, int n) {
    const int sb = blockIdx.x;
    const int tid = threadIdx.x;
    __shared__ int cnt[256], off[256], tmp[256];
    __shared__ int base_sh;
    if (tid < 256) cnt[tid] = 0;
    __syncthreads();

    int len = gcur[sb * CSTR];
    if (len > SBCAP) len = SBCAP;
    const int* seg = arena + (size_t)sb * SBCAP;
    for (int i = tid; i < len; i += 1024)
        atomicAdd(&cnt[seg[i] & 255], 1);
    __syncthreads();

    int v = 0;
    if (tid < 256) { v = cnt[tid]; tmp[tid] = v; }
    __syncthreads();
    for (int o = 1; o < 256; o <<= 1) {
        int t = (tid >= o && tid < 256) ? tmp[tid - o] : 0;
        __syncthreads();
        if (tid < 256) tmp[tid] += t;
        __syncthreads();
    }
    if (tid < 256) off[tid] = tmp[tid] - v;  // exclusive
    if (tid == 255) base_sh = atomicAdd(gcounter, tmp[255]);
    __syncthreads();

    const int base = base_sh;
    if (tid < 256) {
        int node = (sb << SBSH) + tid;
        if (node < n) {
            int r0 = base + off[tid];
            rowptr[node] = r0;
            rowend[node] = r0 + v;
            dinv[node] = rsqrtf((float)v + 1.0f);  // +1 self-loop
        }
    }
    __syncthreads();

    for (int i = tid; i < len; i += 1024) {
        int rec = seg[i];
        int lpos = atomicAdd(&off[rec & 255], 1);
        src_sorted[base + lpos] = rec >> SBSH;
    }
}

// ====== 16-wave single-pass MFMA tiles (verified by R4's passing run) ======
template <int KP, int KOUT, int NTY, bool BIAS, bool OUT_BF16, int OSTR>
__device__ __forceinline__ void mfma_tiles16(const unsigned short* Abf, const unsigned short* Wt,
                                             const float* __restrict__ bias, void* __restrict__ C,
                                             int n, int row0) {
    constexpr int APAD  = KP + 8;
    constexpr int NKC   = KP / 32;
    constexpr int TQ    = (NTY + 1) / 2;
    constexpr int NTALL = (KOUT + 15) / 16;

    const int tid  = threadIdx.x;
    const int lane = tid & 63;
    const int w    = tid >> 6;          // 0..15
    const int m0   = (w >> 1) * 16;     // 16-row strip per wave pair
    const int t0   = (w & 1) * TQ;
    const int lm   = lane & 15;
    const int quad = lane >> 4;
    const int tcnt = (NTALL - t0 < TQ) ? (NTALL - t0) : TQ;

    f32x4 acc[TQ];
    #pragma unroll
    for (int t = 0; t < TQ; ++t) acc[t] = (f32x4)(0.f);

    for (int kt = 0; kt < NKC; ++kt) {
        short8 a = *(const short8*)&Abf[(m0 + lm) * APAD + kt * 32 + quad * 8];
        short8 b[TQ];
        #pragma unroll
        for (int t = 0; t < TQ; ++t)
            if (t < tcnt)
                b[t] = *(const short8*)&Wt[((t0 + t) * 16 + lm) * APAD + kt * 32 + quad * 8];
        #pragma unroll
        for (int t = 0; t < TQ; ++t)
            if (t < tcnt)
                acc[t] = __builtin_amdgcn_mfma_f32_16x16x32_bf16(a, b[t], acc[t], 0, 0, 0);
    }

    #pragma unroll
    for (int t = 0; t < TQ; ++t) {
        if (t >= tcnt) continue;
        int col = (t0 + t) * 16 + lm;
        if (col >= KOUT) continue;
        float bv = 0.f;
        if constexpr (BIAS) bv = bias[col];
        #pragma unroll
        for (int rg = 0; rg < 4; ++rg) {
            int row = row0 + m0 + quad * 4 + rg;
            if (row < n) {
                float v = acc[t][rg] + bv;
                if constexpr (OUT_BF16)
                    ((unsigned short*)C)[(size_t)row * OSTR + col] = f2bf(v);
                else
                    ((float*)C)[(size_t)row * OSTR + col] = v;
            }
        }
    }
}

// ====== fused gather-aggregation + GEMM (R1's proven gather pattern -> LDS A-tile -> MFMA) ======
// Block = 128 output rows. Phase 1: stage Wt. Phase 2: (row,group) work items over 1024 threads;
// each does the CSR unroll-4 gather+register-FMA (measured fast in R0/R1), finalize
// relu(di*(di*h_self + acc) + ab) -> bf16 -> Abf. Phase 3: 16-wave MFMA -> C.
template <int FAGG, int NG, int HSTR, int KIN, int KOUT, int NTY, bool GBIAS, bool OUT_BF16, int OSTR>
__global__ __launch_bounds__(1024) void k_agg_gemm(const unsigned short* __restrict__ h,
                                                   const int* __restrict__ rowptr,
                                                   const int* __restrict__ rowend,
                                                   const int* __restrict__ src_sorted,
                                                   const float* __restrict__ dinv,
                                                   const float* __restrict__ ab,
                                                   const float* __restrict__ W,
                                                   const float* __restrict__ gb,
                                                   void* __restrict__ C, int n) {
    constexpr int KP   = ((KIN + 31) / 32) * 32;
    constexpr int APAD = KP + 8;
    constexpr int NTC  = NTY * 16;
    static_assert(NTC >= ((KOUT + 15) / 16) * 16, "single-pass Wt");
    static_assert(NG * 8 <= KP, "agg cols fit A tile");

    __shared__ __attribute__((aligned(16))) unsigned short Abf[128 * APAD];
    __shared__ __attribute__((aligned(16))) unsigned short Wt[NTC * APAD];

    const int tid  = threadIdx.x;
    const int row0 = blockIdx.x * 128;

    // ---- (1) stage Wt (+k pads) ----
    for (int idx = tid; idx < KIN * NTC; idx += 1024) {
        int k = idx / NTC;
        int c = idx - k * NTC;
        float v = (c < KOUT) ? W[(size_t)k * KOUT + c] : 0.f;
        Wt[c * APAD + k] = f2bf(v);
    }
    if constexpr (KP > KIN) {
        constexpr int PADW = KP - KIN;
        for (int idx = tid; idx < NTC * PADW; idx += 1024) {
            int c = idx / PADW;
            Wt[c * APAD + KIN + (idx - c * PADW)] = 0;
        }
    }

    // ---- (2) gather-aggregate into Abf ----
    for (int idx = tid; idx < 128 * NG; idx += 1024) {
        int r = idx / NG;
        int g = idx - r * NG;
        const int co = g * 8;
        int i = row0 + r;
        u16x8 o;
        #pragma unroll
        for (int j = 0; j < 8; ++j) o[j] = 0;
        if (i < n) {
            const unsigned short* hp = h + co;
            float a[8];
            #pragma unroll
            for (int j = 0; j < 8; ++j) a[j] = 0.f;
            int e = rowptr[i];
            const int end = rowend[i];
            for (; e + 3 < end; e += 4) {
                int s0 = src_sorted[e], s1 = src_sorted[e + 1];
                int s2 = src_sorted[e + 2], s3 = src_sorted[e + 3];
                u16x8 u0 = *(const u16x8*)&hp[(size_t)s0 * HSTR];
                u16x8 u1 = *(const u16x8*)&hp[(size_t)s1 * HSTR];
                u16x8 u2 = *(const u16x8*)&hp[(size_t)s2 * HSTR];
                u16x8 u3 = *(const u16x8*)&hp[(size_t)s3 * HSTR];
                float n0 = dinv[s0], n1 = dinv[s1], n2 = dinv[s2], n3 = dinv[s3];
                #pragma unroll
                for (int j = 0; j < 8; ++j) {
                    a[j] = fmaf(bf2f(u0[j]), n0, a[j]);
                    a[j] = fmaf(bf2f(u1[j]), n1, a[j]);
                    a[j] = fmaf(bf2f(u2[j]), n2, a[j]);
                    a[j] = fmaf(bf2f(u3[j]), n3, a[j]);
                }
            }
            for (; e < end; ++e) {
                int s = src_sorted[e];
                u16x8 u = *(const u16x8*)&hp[(size_t)s * HSTR];
                float nn = dinv[s];
                #pragma unroll
                for (int j = 0; j < 8; ++j) a[j] = fmaf(bf2f(u[j]), nn, a[j]);
            }
            float di = dinv[i];
            u16x8 hs = *(const u16x8*)&hp[(size_t)i * HSTR];
            #pragma unroll
            for (int j = 0; j < 8; ++j) {
                int col = co + j;
                float bj = (col < FAGG) ? ab[col] : 0.f;
                float v = fmaf(di, fmaf(di, bf2f(hs[j]), a[j]), bj);
                o[j] = f2bf(fmaxf(v, 0.f));
            }
        }
        *(u16x8*)&Abf[r * APAD + co] = o;
    }
    if constexpr (KP > NG * 8) {             // zero A pad cols [NG*8, KP)
        constexpr int PW = KP - NG * 8;
        for (int idx = tid; idx < 128 * PW; idx += 1024) {
            int r = idx / PW;
            Abf[r * APAD + NG * 8 + (idx - r * PW)] = 0;
        }
    }
    __syncthreads();

    // ---- (3) GEMM ----
    mfma_tiles16<KP, KOUT, NTY, GBIAS, OUT_BF16, OSTR>(Abf, Wt, gb, C, n, row0);
}

extern "C" void kernel_launch(void* const* d_in, const int* in_sizes, int n_in,
                              void* d_out, int out_size, void* d_ws, size_t ws_size,
                              hipStream_t stream) {
    const float* x  = (const float*)d_in[0];
    const int*   ei = (const int*)d_in[1];
    const float* W1 = (const float*)d_in[2];
    const float* b1 = (const float*)d_in[3];
    const float* W2 = (const float*)d_in[4];
    const float* b2 = (const float*)d_in[5];
    const float* Wc = (const float*)d_in[6];
    const float* bc = (const float*)d_in[7];
    float* out = (float*)d_out;

    const int N = in_sizes[0] / FIN;
    const int E = in_sizes[1] / 2;
    const int* src = ei;
    const int* dst = ei + E;
    const int NSB = (N + 255) >> SBSH;       // 196
    const int SCB = (E + EPB - 1) / EPB;     // 391

    auto align = [](size_t v) { return (v + 255) & ~(size_t)255; };
    char* ws = (char*)d_ws;
    const size_t cur_bytes = align((size_t)256 * CSTR * 4 + 256);
    int*   gcur       = (int*)ws;   ws += cur_bytes;
    int*   gcounter   = gcur + 256 * CSTR;   // inside the memset region
    int*   arena      = (int*)ws;   ws += align((size_t)NSB * SBCAP * 4);
    int*   rowptr     = (int*)ws;   ws += align((size_t)N * 4);
    int*   rowend     = (int*)ws;   ws += align((size_t)N * 4);
    int*   src_sorted = (int*)ws;   ws += align((size_t)E * 4);
    float* dinv       = (float*)ws; ws += align((size_t)N * 4);
    unsigned short* h1 = (unsigned short*)ws; ws += align((size_t)N * H1STR * 2);
    unsigned short* h2 = (unsigned short*)ws; ws += align((size_t)N * FEMB * 2);

    const int nmb = (N + 127) / 128;         // 391 row-tiles

    // 1) zero cursors + gcounter
    hipMemsetAsync(gcur, 0, cur_bytes, stream);

    // 2) merged: edge scatter (blocks [0,SCB)) || GEMM1 h1 = x@W1 (blocks [SCB,SCB+nmb))
    k_front<<<SCB + nmb, 256, 0, stream>>>(src, dst, gcur, arena, E, NSB, SCB, x, W1, h1, N);

    // 3) per-super-bucket sort -> rowptr/rowend/dinv/src_sorted
    k_bucket_sort<<<NSB, 1024, 0, stream>>>(arena, gcur, gcounter, rowptr, rowend, dinv, src_sorted, N);

    // 4) fused: a1 = relu(agg(h1)+b1) -> LDS; h2 = a1 @ W2 (bf16, stride FEMB)
    k_agg_gemm<FHID, 13, H1STR, FHID, FEMB, 4, false, true, FEMB>
        <<<nmb, 1024, 0, stream>>>(h1, rowptr, rowend, src_sorted, dinv, b1, W2, nullptr, h2, N);

    // 5) fused: a2 = relu(agg(h2)+b2) -> LDS; out = a2 @ Wc + bc (fp32)
    k_agg_gemm<FEMB, 8, FEMB, FEMB, NCLS, 3, true, false, NCLS>
        <<<nmb, 1024, 0, stream>>>(h2, rowptr, rowend, src_sorted, dinv, b2, Wc, bc, out, N);
}